// Round 1
// baseline (761.947 us; speedup 1.0000x reference)
//
#include <hip/hip_runtime.h>
#include <hip/hip_bf16.h>
#include <stdint.h>

// Problem constants (fixed by reference setup_inputs)
#define T_ 800
#define B_ 16
#define D_ 256
#define V_ 4001
#define U_ 100
#define S_ 201      // 2U+1
#define SP 204      // S padded to multiple of 4 for float4 loads in alpha
#define M_ (T_*B_)  // 12800 GEMM rows
#define NEGF (-1e30f)
#define L2E 1.4426950408889634f
#define LN2 0.6931471805599453f

typedef __bf16 bf16;
typedef __bf16 bf16x8 __attribute__((ext_vector_type(8)));
typedef float f32x4 __attribute__((ext_vector_type(4)));

// Workspace layout (bytes). Total ~19.2 MB.
#define A_OFF     0          // bf16 A[12800][256]            6,553,600
#define WT_OFF    6553600    // bf16 Wt[4096][256] (padded)   2,097,152
#define EMIT_OFF  8650752    // f32 emit[12800][204] (log2!) 10,444,800
#define EXT_OFF   19095552   // i32 ext[16][204]                 13,056
#define AMASK_OFF 19108608   // f32 amask[16][204]               13,056
#define LENS_OFF  19121664   // i32 lens[16]

// ---------------- prep: ext labels, allow-mask, label lens, zero loss ----
__global__ void prep_kernel(const int* __restrict__ y, float* __restrict__ out,
                            int* __restrict__ ext, float* __restrict__ amask,
                            int* __restrict__ lens) {
  const int tid = threadIdx.x;
  if (tid == 0) out[0] = 0.f;  // loss accumulator (alpha atomicAdds later)
  if (tid < B_) {
    int cnt = 0;
    for (int u = 0; u < U_; u++) cnt += (y[u*B_ + tid] != 1) ? 1 : 0;
    lens[tid] = cnt;
  }
  for (int idx = tid; idx < B_*SP; idx += 256) {
    int b = idx / SP, s = idx - b*SP;
    int e = 0;
    if (s < S_ && (s & 1)) e = y[((s-1) >> 1)*B_ + b];
    ext[idx] = e;
    float am = NEGF;  // additive mask for the s-2 transition
    if ((s & 1) && s >= 3 && s < S_) {
      int e2 = y[((s-3) >> 1)*B_ + b];
      if (e != 0 && e != e2) am = 0.f;
    }
    amask[idx] = am;
  }
}

// ---------------- cast ctx (f32) -> A (bf16), element-wise ---------------
__global__ void cast_a_kernel(const float* __restrict__ ctx, bf16* __restrict__ A) {
  int i = blockIdx.x * blockDim.x + threadIdx.x;  // exactly 819200 threads
  float4 v = ((const float4*)ctx)[i];
  union { bf16 h[4]; uint2 u; } p;
  p.h[0] = (bf16)v.x; p.h[1] = (bf16)v.y; p.h[2] = (bf16)v.z; p.h[3] = (bf16)v.w;
  ((uint2*)A)[i] = p.u;
}

// ---------------- transpose W [256][4001] f32 -> Wt [4096][256] bf16 -----
__global__ void trans_w_kernel(const float* __restrict__ W, bf16* __restrict__ Wt) {
  __shared__ float tile[32][33];
  const int c = threadIdx.x & 31, r = threadIdx.x >> 5;  // 32x8 threads
  const int n0 = blockIdx.x * 32, k0 = blockIdx.y * 32;
  for (int rr = r; rr < 32; rr += 8) {
    int n = n0 + c;
    tile[rr][c] = (n < V_) ? W[(size_t)(k0+rr)*V_ + n] : 0.f;
  }
  __syncthreads();
  for (int rr = r; rr < 32; rr += 8) {
    Wt[(size_t)(n0+rr)*D_ + k0 + c] = (bf16)tile[c][rr];
  }
}

// ---------------- GEMM: logits = A x Wt^T + bias -> out[1..] (f32) -------
// 128x128 tile, BK=64, mfma_f32_16x16x32_bf16, wave tile 64x64 (4x4 C-tiles)
// LDS row stride 72 bf16 (144 B = 9*16 B) -> bank-uniform b128 reads.
__global__ __launch_bounds__(256) void gemm_kernel(
    const bf16* __restrict__ A, const bf16* __restrict__ Wt,
    const float* __restrict__ bias, float* __restrict__ out) {
  __shared__ bf16 smA[128*72];
  __shared__ bf16 smB[128*72];
  const int tid = threadIdx.x;
  const int l = tid & 63, w = tid >> 6;
  const int wr = w >> 1, wc = w & 1;
  const int n0 = blockIdx.x * 128, m0 = blockIdx.y * 128;

  f32x4 acc[4][4];
#pragma unroll
  for (int i = 0; i < 4; i++)
#pragma unroll
    for (int j = 0; j < 4; j++) acc[i][j] = (f32x4){0.f, 0.f, 0.f, 0.f};

  for (int kt = 0; kt < 4; kt++) {
    // stage 128x64 bf16 tiles of A and Wt (Wt rows are N, k-contiguous)
#pragma unroll
    for (int r = 0; r < 4; r++) {
      int j = (w*4 + r)*64 + l;        // 0..1023 16B-chunk slot
      int row = j >> 3, c = j & 7;     // row 0..127, chunk 0..7 (8 bf16)
      bf16x8 va = *(const bf16x8*)(A  + (size_t)(m0+row)*D_ + kt*64 + c*8);
      bf16x8 vb = *(const bf16x8*)(Wt + (size_t)(n0+row)*D_ + kt*64 + c*8);
      *(bf16x8*)((char*)smA + row*144 + (c<<4)) = va;
      *(bf16x8*)((char*)smB + row*144 + (c<<4)) = vb;
    }
    __syncthreads();
#pragma unroll
    for (int ks = 0; ks < 2; ks++) {
      bf16x8 af[4], bfr[4];
      const int cidx = ks*4 + (l >> 4);  // 16B chunk along k (A layout: k=quad*8+j)
#pragma unroll
      for (int t = 0; t < 4; t++) {
        int arow = wr*64 + t*16 + (l & 15);
        af[t]  = *(const bf16x8*)((const char*)smA + arow*144 + (cidx<<4));
        int brow = wc*64 + t*16 + (l & 15);
        bfr[t] = *(const bf16x8*)((const char*)smB + brow*144 + (cidx<<4));
      }
#pragma unroll
      for (int i = 0; i < 4; i++)
#pragma unroll
        for (int j = 0; j < 4; j++)
          acc[i][j] = __builtin_amdgcn_mfma_f32_16x16x32_bf16(af[i], bfr[j], acc[i][j], 0, 0, 0);
    }
    __syncthreads();
  }
  // epilogue: C layout col=lane&15, row=(lane>>4)*4+reg (verified m89/m91)
#pragma unroll
  for (int j = 0; j < 4; j++) {
    int gn = n0 + wc*64 + j*16 + (l & 15);
    if (gn < V_) {
      float bv = bias[gn];
#pragma unroll
      for (int i = 0; i < 4; i++) {
        int rbase = m0 + wr*64 + i*16 + ((l >> 4) << 2);
#pragma unroll
        for (int rg = 0; rg < 4; rg++) {
          out[1 + (size_t)(rbase + rg)*V_ + gn] = acc[i][j][rg] + bv;
        }
      }
    }
  }
}

// ---------------- per-row log_softmax in place + emit gather -------------
__global__ __launch_bounds__(256) void softmax_gather_kernel(
    float* __restrict__ out, const int* __restrict__ ext, float* __restrict__ emit) {
  __shared__ float srow[4096];
  __shared__ float red[8];
  const int row = blockIdx.x, tid = threadIdx.x;
  float* rp = out + 1 + (size_t)row * V_;
  float v[16];
  float mx = NEGF;
#pragma unroll
  for (int j = 0; j < 16; j++) {
    int c = tid + j*256;
    v[j] = (c < V_) ? rp[c] : NEGF;
    mx = fmaxf(mx, v[j]);
  }
#pragma unroll
  for (int o = 32; o > 0; o >>= 1) mx = fmaxf(mx, __shfl_xor(mx, o));
  if ((tid & 63) == 0) red[tid >> 6] = mx;
  __syncthreads();
  mx = fmaxf(fmaxf(red[0], red[1]), fmaxf(red[2], red[3]));
  float sm = 0.f;
#pragma unroll
  for (int j = 0; j < 16; j++) sm += exp2f((v[j] - mx) * L2E);
#pragma unroll
  for (int o = 32; o > 0; o >>= 1) sm += __shfl_xor(sm, o);
  if ((tid & 63) == 0) red[4 + (tid >> 6)] = sm;
  __syncthreads();
  const float lse = mx + log2f(red[4] + red[5] + red[6] + red[7]) * LN2;
#pragma unroll
  for (int j = 0; j < 16; j++) {
    int c = tid + j*256;
    if (c < V_) {
      float lp = v[j] - lse;
      rp[c] = lp;        // final logps output
      srow[c] = lp;      // for the emit gather below
    }
  }
  __syncthreads();
  // emit stored pre-scaled by log2(e): alpha runs in log2 domain
  if (tid < SP) {
    float e = NEGF;
    if (tid < S_) e = srow[ext[(row & (B_-1))*SP + tid]] * L2E;
    emit[(size_t)row*SP + tid] = e;
  }
}

// ---------------- CTC alpha recursion (log2 domain), one wave per batch --
__device__ __forceinline__ float lae3_2(float a, float b, float c) {
  float m = fmaxf(fmaxf(a, b), c);
  float s = exp2f(a - m) + exp2f(b - m) + exp2f(c - m);
  return m + log2f(s);
}

__global__ __launch_bounds__(64) void alpha_kernel(
    const float* __restrict__ emit, const float* __restrict__ amask,
    const int* __restrict__ lens, float* __restrict__ out) {
  __shared__ float aS[256];
  const int b = blockIdx.x, l = threadIdx.x;
  const bool act = (l < 51);  // 51*4 = 204 >= S
  const float4 NEG4 = make_float4(NEGF, NEGF, NEGF, NEGF);
  const float* ep = emit + (size_t)b*SP + 4*l;
  const float4 am = act ? *(const float4*)(amask + b*SP + 4*l) : NEG4;
  float4 cur = act ? *(const float4*)ep : NEG4;           // t=0
  // alpha0: only s=0,1 reachable (lane 0 regs .x/.y)
  float a0 = (l == 0) ? cur.x : NEGF;
  float a1 = (l == 0) ? cur.y : NEGF;
  float a2 = NEGF, a3 = NEGF;
  float4 nxt = act ? *(const float4*)(ep + B_*SP) : NEG4;  // prefetch t=1
  for (int t = 1; t < T_; t++) {
    cur = nxt;
    if (t + 1 < T_) nxt = act ? *(const float4*)(ep + (size_t)(t+1)*(B_*SP)) : NEG4;
    float sh1 = __shfl_up(a3, 1);  // alpha[s-1] for j=0 (prev lane j=3)
    float sh2 = __shfl_up(a2, 1);  // alpha[s-2] for j=0 (prev lane j=2)
    if (l == 0) { sh1 = NEGF; sh2 = NEGF; }
    float n0 = lae3_2(a0, sh1, sh2 + am.x) + cur.x;
    float n1 = lae3_2(a1, a0,  sh1 + am.y) + cur.y;
    float n2 = lae3_2(a2, a1,  a0  + am.z) + cur.z;
    float n3 = lae3_2(a3, a2,  a1  + am.w) + cur.w;
    a0 = n0; a1 = n1; a2 = n2; a3 = n3;
  }
  aS[4*l+0] = a0; aS[4*l+1] = a1; aS[4*l+2] = a2; aS[4*l+3] = a3;
  __syncthreads();
  if (l == 0) {
    int e = 2 * lens[b];
    float la = aS[e], lb = aS[e-1];
    float m = fmaxf(la, lb);
    float ll2 = m + log2f(exp2f(la - m) + exp2f(lb - m));
    atomicAdd(out, -ll2 * LN2);  // loss = -sum_b ll
  }
}

// ---------------- launch ----------------
extern "C" void kernel_launch(void* const* d_in, const int* in_sizes, int n_in,
                              void* d_out, int out_size, void* d_ws, size_t ws_size,
                              hipStream_t stream) {
  const float* ctx  = (const float*)d_in[0];  // [800,16,256]
  const int*   y    = (const int*)  d_in[1];  // [100,16]
  const float* W    = (const float*)d_in[2];  // [256,4001]
  const float* bias = (const float*)d_in[3];  // [4001]
  float* out = (float*)d_out;                 // [1 + 800*16*4001]
  char* ws = (char*)d_ws;
  bf16*  A     = (bf16*) (ws + A_OFF);
  bf16*  Wt    = (bf16*) (ws + WT_OFF);
  float* emit  = (float*)(ws + EMIT_OFF);
  int*   ext   = (int*)  (ws + EXT_OFF);
  float* amask = (float*)(ws + AMASK_OFF);
  int*   lens  = (int*)  (ws + LENS_OFF);

  hipLaunchKernelGGL(prep_kernel, dim3(1), dim3(256), 0, stream, y, out, ext, amask, lens);
  hipLaunchKernelGGL(cast_a_kernel, dim3(3200), dim3(256), 0, stream, ctx, A);
  hipLaunchKernelGGL(trans_w_kernel, dim3(128, 8), dim3(256), 0, stream, W, Wt);
  hipLaunchKernelGGL(gemm_kernel, dim3(32, 100), dim3(256), 0, stream, A, Wt, bias, out);
  hipLaunchKernelGGL(softmax_gather_kernel, dim3(12800), dim3(256), 0, stream, out, ext, emit);
  hipLaunchKernelGGL(alpha_kernel, dim3(16), dim3(64), 0, stream, emit, amask, lens, out);
}

// Round 3
// 590.955 us; speedup vs baseline: 1.2893x; 1.2893x over previous
//
#include <hip/hip_runtime.h>
#include <hip/hip_bf16.h>
#include <stdint.h>

// Problem constants (fixed by reference setup_inputs)
#define T_ 800
#define B_ 16
#define D_ 256
#define V_ 4001
#define U_ 100
#define S_ 201      // 2U+1
#define SP 204      // S padded to multiple of 4 for float4 loads in alpha
#define M_ (T_*B_)  // 12800 GEMM rows
#define NEGF (-1e30f)
#define L2E 1.4426950408889634f
#define LN2 0.6931471805599453f

typedef __bf16 bf16;
typedef __bf16 bf16x8 __attribute__((ext_vector_type(8)));
typedef float f32x4 __attribute__((ext_vector_type(4)));

// Workspace layout (bytes). Total ~19.2 MB.
#define A_OFF     0          // bf16 A[12800][256]            6,553,600
#define WT_OFF    6553600    // bf16 Wt[4096][256] (padded)   2,097,152
#define EMIT_OFF  8650752    // f32 emit[B][T][SP] (log2 domain) 10,444,800
#define EXT_OFF   19095552   // i32 ext[16][204]                 13,056
#define AMASK_OFF 19108608   // f32 amask[16][204] (additive)    13,056
#define LENS_OFF  19121664   // i32 lens[16]

// ---------------- prep: ext labels, allow-mask (additive), label lens ----
__global__ void prep_kernel(const int* __restrict__ y, float* __restrict__ out,
                            int* __restrict__ ext, float* __restrict__ amask,
                            int* __restrict__ lens) {
  const int tid = threadIdx.x;
  if (tid == 0) out[0] = 0.f;  // loss accumulator (alpha atomicAdds later)
  if (tid < B_) {
    int cnt = 0;
    for (int u = 0; u < U_; u++) cnt += (y[u*B_ + tid] != 1) ? 1 : 0;
    lens[tid] = cnt;
  }
  for (int idx = tid; idx < B_*SP; idx += 256) {
    int b = idx / SP, s = idx - b*SP;
    int e = 0;
    if (s < S_ && (s & 1)) e = y[((s-1) >> 1)*B_ + b];
    ext[idx] = e;
    float am = NEGF;  // additive mask for the s-2 transition (log domain)
    if ((s & 1) && s >= 3 && s < S_) {
      int e2 = y[((s-3) >> 1)*B_ + b];
      if (e != 0 && e != e2) am = 0.f;
    }
    amask[idx] = am;
  }
}

// ---------------- cast ctx (f32) -> A (bf16), element-wise ---------------
__global__ void cast_a_kernel(const float* __restrict__ ctx, bf16* __restrict__ A) {
  int i = blockIdx.x * blockDim.x + threadIdx.x;  // exactly 819200 threads
  float4 v = ((const float4*)ctx)[i];
  union { bf16 h[4]; uint2 u; } p;
  p.h[0] = (bf16)v.x; p.h[1] = (bf16)v.y; p.h[2] = (bf16)v.z; p.h[3] = (bf16)v.w;
  ((uint2*)A)[i] = p.u;
}

// ---------------- transpose W [256][4001] f32 -> Wt [4096][256] bf16 -----
__global__ void trans_w_kernel(const float* __restrict__ W, bf16* __restrict__ Wt) {
  __shared__ float tile[32][33];
  const int c = threadIdx.x & 31, r = threadIdx.x >> 5;  // 32x8 threads
  const int n0 = blockIdx.x * 32, k0 = blockIdx.y * 32;
  for (int rr = r; rr < 32; rr += 8) {
    int n = n0 + c;
    tile[rr][c] = (n < V_) ? W[(size_t)(k0+rr)*V_ + n] : 0.f;
  }
  __syncthreads();
  for (int rr = r; rr < 32; rr += 8) {
    Wt[(size_t)(n0+rr)*D_ + k0 + c] = (bf16)tile[c][rr];
  }
}

// ---------------- GEMM: logits = A x Wt^T + bias -> out[1..] (f32) -------
// 128x128 tile, BK=64, mfma_f32_16x16x32_bf16, wave tile 64x64 (4x4 C-tiles)
// LDS row stride 72 bf16 (144 B = 9*16 B) -> bank-uniform b128 reads.
__global__ __launch_bounds__(256) void gemm_kernel(
    const bf16* __restrict__ A, const bf16* __restrict__ Wt,
    const float* __restrict__ bias, float* __restrict__ out) {
  __shared__ bf16 smA[128*72];
  __shared__ bf16 smB[128*72];
  const int tid = threadIdx.x;
  const int l = tid & 63, w = tid >> 6;
  const int wr = w >> 1, wc = w & 1;
  const int n0 = blockIdx.x * 128, m0 = blockIdx.y * 128;

  f32x4 acc[4][4];
#pragma unroll
  for (int i = 0; i < 4; i++)
#pragma unroll
    for (int j = 0; j < 4; j++) acc[i][j] = (f32x4){0.f, 0.f, 0.f, 0.f};

  for (int kt = 0; kt < 4; kt++) {
#pragma unroll
    for (int r = 0; r < 4; r++) {
      int j = (w*4 + r)*64 + l;        // 0..1023 16B-chunk slot
      int row = j >> 3, c = j & 7;     // row 0..127, chunk 0..7 (8 bf16)
      bf16x8 va = *(const bf16x8*)(A  + (size_t)(m0+row)*D_ + kt*64 + c*8);
      bf16x8 vb = *(const bf16x8*)(Wt + (size_t)(n0+row)*D_ + kt*64 + c*8);
      *(bf16x8*)((char*)smA + row*144 + (c<<4)) = va;
      *(bf16x8*)((char*)smB + row*144 + (c<<4)) = vb;
    }
    __syncthreads();
#pragma unroll
    for (int ks = 0; ks < 2; ks++) {
      bf16x8 af[4], bfr[4];
      const int cidx = ks*4 + (l >> 4);
#pragma unroll
      for (int t = 0; t < 4; t++) {
        int arow = wr*64 + t*16 + (l & 15);
        af[t]  = *(const bf16x8*)((const char*)smA + arow*144 + (cidx<<4));
        int brow = wc*64 + t*16 + (l & 15);
        bfr[t] = *(const bf16x8*)((const char*)smB + brow*144 + (cidx<<4));
      }
#pragma unroll
      for (int i = 0; i < 4; i++)
#pragma unroll
        for (int j = 0; j < 4; j++)
          acc[i][j] = __builtin_amdgcn_mfma_f32_16x16x32_bf16(af[i], bfr[j], acc[i][j], 0, 0, 0);
    }
    __syncthreads();
  }
  // epilogue: C layout col=lane&15, row=(lane>>4)*4+reg (verified m89/m91)
#pragma unroll
  for (int j = 0; j < 4; j++) {
    int gn = n0 + wc*64 + j*16 + (l & 15);
    if (gn < V_) {
      float bv = bias[gn];
#pragma unroll
      for (int i = 0; i < 4; i++) {
        int rbase = m0 + wr*64 + i*16 + ((l >> 4) << 2);
#pragma unroll
        for (int rg = 0; rg < 4; rg++) {
          out[1 + (size_t)(rbase + rg)*V_ + gn] = acc[i][j][rg] + bv;
        }
      }
    }
  }
}

// ---------------- per-row log_softmax in place + emit gather -------------
// emit stored TRANSPOSED [b][t][SP], log2 domain (pre-scaled by log2(e)).
__global__ __launch_bounds__(256) void softmax_gather_kernel(
    float* __restrict__ out, const int* __restrict__ ext, float* __restrict__ emit) {
  __shared__ float srow[4096];
  __shared__ float red[8];
  const int row = blockIdx.x, tid = threadIdx.x;
  float* rp = out + 1 + (size_t)row * V_;
  float v[16];
  float mx = NEGF;
#pragma unroll
  for (int j = 0; j < 16; j++) {
    int c = tid + j*256;
    v[j] = (c < V_) ? rp[c] : NEGF;
    mx = fmaxf(mx, v[j]);
  }
#pragma unroll
  for (int o = 32; o > 0; o >>= 1) mx = fmaxf(mx, __shfl_xor(mx, o));
  if ((tid & 63) == 0) red[tid >> 6] = mx;
  __syncthreads();
  mx = fmaxf(fmaxf(red[0], red[1]), fmaxf(red[2], red[3]));
  float sm = 0.f;
#pragma unroll
  for (int j = 0; j < 16; j++) sm += exp2f((v[j] - mx) * L2E);
#pragma unroll
  for (int o = 32; o > 0; o >>= 1) sm += __shfl_xor(sm, o);
  if ((tid & 63) == 0) red[4 + (tid >> 6)] = sm;
  __syncthreads();
  const float lse = mx + log2f(red[4] + red[5] + red[6] + red[7]) * LN2;
#pragma unroll
  for (int j = 0; j < 16; j++) {
    int c = tid + j*256;
    if (c < V_) {
      float lp = v[j] - lse;
      rp[c] = lp;        // final logps output
      srow[c] = lp;      // for the emit gather below
    }
  }
  __syncthreads();
  // emit in log2 domain: alpha runs in log2, avoids mul-by-L2E per step
  if (tid < SP) {
    float e = NEGF;
    if (tid < S_) e = srow[ext[(row & (B_-1))*SP + tid]] * L2E;
    emit[((size_t)(row & (B_-1))*T_ + (row >> 4))*SP + tid] = e;
  }
}

// ---------------- CTC alpha recursion (log2 domain), one wave per batch --
// 16-deep float4 prefetch pipeline hides ~900-cycle HBM latency (R1 was
// prefetch-distance-1 -> 424 us latency-bound; counters: VALUBusy 0.74%).
__device__ __forceinline__ float lae3_2(float a, float b, float c) {
  float m = fmaxf(fmaxf(a, b), c);
  float s = exp2f(a - m) + exp2f(b - m) + exp2f(c - m);
  return m + log2f(s);
}

__global__ __launch_bounds__(64) void alpha_kernel(
    const float* __restrict__ emit, const float* __restrict__ amp,
    const int* __restrict__ lens, float* __restrict__ out) {
  __shared__ float aS[256];
  const int b = blockIdx.x, l = threadIdx.x;
  const bool act = (l < 51);  // 51*4 = 204 = SP
  const float4 NEG4 = make_float4(NEGF, NEGF, NEGF, NEGF);
  const float* ep = emit + (size_t)b*T_*SP + 4*l;  // lane base at t=0
  const float4 am = act ? *(const float4*)(amp + b*SP + 4*l) : NEG4;
  const float4 e0 = act ? *(const float4*)ep : NEG4;
  // alpha0: only s=0,1 reachable
  float a0 = (l == 0) ? e0.x : NEGF;
  float a1 = (l == 0) ? e0.y : NEGF;
  float a2 = NEGF, a3 = NEGF;

  // prefetch pipeline: buf[j] holds emissions for t = (chunk base)+j
  float4 buf[16];
#pragma unroll
  for (int j = 0; j < 16; j++)
    buf[j] = act ? *(const float4*)(ep + (size_t)(1 + j)*SP) : NEG4;

  auto step = [&](int slot, int t, bool pf) {
    float4 cur = buf[slot];
    float4 nv = NEG4;
    if (pf) {
      int tp = t + 16; if (tp > T_-1) tp = T_-1;
      nv = act ? *(const float4*)(ep + (size_t)tp*SP) : NEG4;
    }
    float sh1 = __shfl_up(a3, 1);  // alpha[s-1] for state 4l
    float sh2 = __shfl_up(a2, 1);  // alpha[s-2] for state 4l
    if (l == 0) { sh1 = NEGF; sh2 = NEGF; }
    float n0 = lae3_2(a0, sh1, sh2 + am.x) + cur.x;
    float n1 = lae3_2(a1, a0,  sh1 + am.y) + cur.y;
    float n2 = lae3_2(a2, a1,  a0  + am.z) + cur.z;
    float n3 = lae3_2(a3, a2,  a1  + am.w) + cur.w;
    a0 = n0; a1 = n1; a2 = n2; a3 = n3;
    if (pf) buf[slot] = nv;
  };

  // main: 49 chunks of 16 steps -> t = 1..784
  for (int c = 0; c < 49; c++) {
    const int tb = 1 + c*16;
#pragma unroll
    for (int j = 0; j < 16; j++) step(j, tb + j, true);
  }
  // tail: t = 785..799 live in slots 0..14
#pragma unroll
  for (int j = 0; j < 15; j++) step(j, 785 + j, false);

  aS[4*l+0] = a0; aS[4*l+1] = a1; aS[4*l+2] = a2; aS[4*l+3] = a3;
  __syncthreads();
  if (l == 0) {
    int e = 2 * lens[b];
    float la = aS[e], lb = aS[e-1];
    float m = fmaxf(la, lb);
    float ll2 = m + log2f(exp2f(la - m) + exp2f(lb - m));
    atomicAdd(out, -ll2 * LN2);  // loss = -sum_b ll
  }
}

// ---------------- launch ----------------
extern "C" void kernel_launch(void* const* d_in, const int* in_sizes, int n_in,
                              void* d_out, int out_size, void* d_ws, size_t ws_size,
                              hipStream_t stream) {
  const float* ctx  = (const float*)d_in[0];  // [800,16,256]
  const int*   y    = (const int*)  d_in[1];  // [100,16]
  const float* W    = (const float*)d_in[2];  // [256,4001]
  const float* bias = (const float*)d_in[3];  // [4001]
  float* out = (float*)d_out;                 // [1 + 800*16*4001]
  char* ws = (char*)d_ws;
  bf16*  A     = (bf16*) (ws + A_OFF);
  bf16*  Wt    = (bf16*) (ws + WT_OFF);
  float* emit  = (float*)(ws + EMIT_OFF);
  int*   ext   = (int*)  (ws + EXT_OFF);
  float* amp   = (float*)(ws + AMASK_OFF);
  int*   lens  = (int*)  (ws + LENS_OFF);

  hipLaunchKernelGGL(prep_kernel, dim3(1), dim3(256), 0, stream, y, out, ext, amp, lens);
  hipLaunchKernelGGL(cast_a_kernel, dim3(3200), dim3(256), 0, stream, ctx, A);
  hipLaunchKernelGGL(trans_w_kernel, dim3(128, 8), dim3(256), 0, stream, W, Wt);
  hipLaunchKernelGGL(gemm_kernel, dim3(32, 100), dim3(256), 0, stream, A, Wt, bias, out);
  hipLaunchKernelGGL(softmax_gather_kernel, dim3(12800), dim3(256), 0, stream, out, ext, emit);
  hipLaunchKernelGGL(alpha_kernel, dim3(16), dim3(64), 0, stream, emit, amp, lens, out);
}